// Round 6
// baseline (181.479 us; speedup 1.0000x reference)
//
#include <hip/hip_runtime.h>
#include <hip/hip_cooperative_groups.h>
#include <hip/hip_bf16.h>
#include <stdint.h>

namespace cg = cooperative_groups;

// LogLinearCDE: out = softmax(W_out @ (y0 * prod_l flows[l]) + b_out)
// flows[l,h] = 1 + sum_c logsigs[l,c]*vf_A[c,h];  y0 = W_in@x0 + b_in
// R6: ONE cooperative kernel. P0 pack vf_A->bf16 hi/lo (16 blocks, overlapped
// with per-block LDS A-staging) | grid.sync | P1 MFMA partial products per
// 64-row chunk (R4 structure, 4 blocks/CU) | grid.sync | P2 reduce+head with
// last-block fence pattern. Eliminates 4 inter-kernel launch gaps.

#define LSTEPS 16384
#define HID    4096
#define CC     17
#define NLAB   10
#define NW     16          // packed u32 words per col (K padded to 32 bf16)
#define NCHUNK 256
#define CR     64          // rows per chunk
#define APAD   20          // LDS A row stride in words (80B, 16B-aligned)
#define HPB    16          // h per reduce block
#define RBLK   256         // reduce blocks

typedef __attribute__((ext_vector_type(8))) short short8;
typedef __attribute__((ext_vector_type(4))) float f32x4;

static __device__ __forceinline__ unsigned short f2bf(float x) {
  __hip_bfloat16 h = __float2bfloat16(x);
  return *reinterpret_cast<unsigned short*>(&h);
}
static __device__ __forceinline__ float bf2f(unsigned short u) {
  __hip_bfloat16 h; *reinterpret_cast<unsigned short*>(&h) = u;
  return __bfloat162float(h);
}
static __device__ __forceinline__ uint32_t pack_hi(float v0, float v1) {
  return (uint32_t)f2bf(v0) | ((uint32_t)f2bf(v1) << 16);
}
static __device__ __forceinline__ uint32_t pack_lo(float v0, float v1) {
  float r0 = v0 - bf2f(f2bf(v0)), r1 = v1 - bf2f(f2bf(v1));
  return (uint32_t)f2bf(r0) | ((uint32_t)f2bf(r1) << 16);
}

__global__ __launch_bounds__(256, 4) void fused_kernel(
    const float* __restrict__ logsigs, const float* __restrict__ vfA,
    const float* __restrict__ Win, const float* __restrict__ bin,
    const float* __restrict__ x0,  const float* __restrict__ Wout,
    const float* __restrict__ bout,
    float* __restrict__ ws_p, uint32_t* __restrict__ pBh,
    uint32_t* __restrict__ pBl, float* __restrict__ ws_lp,
    uint32_t* __restrict__ cnt, float* __restrict__ out) {
  const int b = blockIdx.x, tid = threadIdx.x;
  const int nblk = gridDim.x;

  __shared__ __align__(16) uint32_t sAh[CR][APAD], sAl[CR][APAD];
  __shared__ float sp[HPB][17];
  __shared__ float sy[HPB];
  __shared__ float slog[NLAB];
  __shared__ bool isLast;

  const int hb = b & 3;
  const int chunk0 = b >> 2;
  const int cstep = nblk >> 2;

  // ---- stage A for chunk0 into LDS (independent of pack, overlaps P0)
  {
    const float* __restrict__ src = logsigs + (size_t)chunk0*CR*CC;
    for (int e = tid; e < CR*NW; e += 256) {
      const int r = e >> 4, j = e & (NW-1);
      const int k0 = 2*j, k1 = k0 + 1;
      const float v0 = (k0 < CC) ? src[r*CC + k0] : 0.0f;
      const float v1 = (k1 < CC) ? src[r*CC + k1] : 0.0f;
      sAh[r][j] = pack_hi(v0, v1);
      sAl[r][j] = pack_lo(v0, v1);
    }
  }
  // ---- P0: pack vf_A (blocks 0..15); zero counter
  if (b == 0 && tid == 0) *cnt = 0u;
  if (b < 16) {
    const int c = b*256 + tid;
    float v[2*NW];
    #pragma unroll
    for (int k = 0; k < 2*NW; ++k) v[k] = (k < CC) ? vfA[k*HID + c] : 0.0f;
    #pragma unroll
    for (int j = 0; j < NW; ++j) {
      pBh[(size_t)c*NW + j] = pack_hi(v[2*j], v[2*j+1]);
      pBl[(size_t)c*NW + j] = pack_lo(v[2*j], v[2*j+1]);
    }
  }
  cg::this_grid().sync();

  // ---- P1: MFMA partial products, grid-stride over chunks
  const int wv = tid >> 6, lane = tid & 63;
  const int g = lane >> 4, cr = lane & 15;
  const int cbase = hb*1024 + wv*256;

  for (int chunk = chunk0; chunk < NCHUNK; chunk += cstep) {
    if (chunk != chunk0) {
      __syncthreads();   // previous readers done with LDS
      const float* __restrict__ src = logsigs + (size_t)chunk*CR*CC;
      for (int e = tid; e < CR*NW; e += 256) {
        const int r = e >> 4, j = e & (NW-1);
        const int k0 = 2*j, k1 = k0 + 1;
        const float v0 = (k0 < CC) ? src[r*CC + k0] : 0.0f;
        const float v1 = (k1 < CC) ? src[r*CC + k1] : 0.0f;
        sAh[r][j] = pack_hi(v0, v1);
        sAl[r][j] = pack_lo(v0, v1);
      }
      __syncthreads();
    }
    short8 Ah[4], Al[4];
    #pragma unroll
    for (int mt = 0; mt < 4; ++mt) {
      const int r = mt*16 + cr;
      Ah[mt] = *reinterpret_cast<const short8*>(&sAh[r][4*g]);
      Al[mt] = *reinterpret_cast<const short8*>(&sAl[r][4*g]);
    }
    #pragma unroll 2
    for (int nt = 0; nt < 16; ++nt) {
      const int c = cbase + nt*16 + cr;
      const short8 Bh = *reinterpret_cast<const short8*>(&pBh[(size_t)c*NW + 4*g]);
      const short8 Bl = *reinterpret_cast<const short8*>(&pBl[(size_t)c*NW + 4*g]);
      float pcol = 1.0f;
      #pragma unroll
      for (int mt = 0; mt < 4; ++mt) {
        f32x4 acc = {0.0f, 0.0f, 0.0f, 0.0f};
        acc = __builtin_amdgcn_mfma_f32_16x16x32_bf16(Ah[mt], Bh, acc, 0, 0, 0);
        acc = __builtin_amdgcn_mfma_f32_16x16x32_bf16(Ah[mt], Bl, acc, 0, 0, 0);
        acc = __builtin_amdgcn_mfma_f32_16x16x32_bf16(Al[mt], Bh, acc, 0, 0, 0);
        pcol *= (1.0f + acc[0]) * (1.0f + acc[1]) * (1.0f + acc[2]) * (1.0f + acc[3]);
      }
      pcol *= __shfl_xor(pcol, 16, 64);
      pcol *= __shfl_xor(pcol, 32, 64);
      if (g == 0) ws_p[(size_t)chunk*HID + c] = pcol;
    }
  }
  cg::this_grid().sync();

  // ---- P2: reduce + head (blocks 0..255)
  if (b < RBLK) {
    const int h0 = b * HPB;
    const int hh = tid & 15, sl = tid >> 4;   // consecutive tid -> consecutive h
    float pprod = 1.0f;
    #pragma unroll
    for (int i = 0; i < 16; ++i)
      pprod *= ws_p[(size_t)(sl*16 + i)*HID + h0 + hh];
    sp[hh][sl] = pprod;
    __syncthreads();

    if (tid < HPB) {
      float P = 1.0f;
      #pragma unroll
      for (int s = 0; s < 16; ++s) P *= sp[tid][s];
      const int h = h0 + tid;
      const float4* __restrict__ wrow = reinterpret_cast<const float4*>(Win + (size_t)h*16);
      float y = bin[h];
      #pragma unroll
      for (int q = 0; q < 4; ++q) {
        float4 w = wrow[q];
        y = fmaf(w.x, x0[q*4+0], y);
        y = fmaf(w.y, x0[q*4+1], y);
        y = fmaf(w.z, x0[q*4+2], y);
        y = fmaf(w.w, x0[q*4+3], y);
      }
      sy[tid] = y * P;
    }
    __syncthreads();

    if (tid < NLAB*HPB) {                  // 160 threads: j x 16 h-slots
      const int j = tid >> 4, k = tid & 15;
      float v = Wout[(size_t)j*HID + h0 + k] * sy[k];
      v += __shfl_xor(v, 1, 64);
      v += __shfl_xor(v, 2, 64);
      v += __shfl_xor(v, 4, 64);
      v += __shfl_xor(v, 8, 64);
      if (k == 0) ws_lp[b*16 + j] = v;
    }
    __threadfence();
    __syncthreads();
    if (tid == 0) isLast = (atomicAdd(cnt, 1u) == RBLK - 1);
    __syncthreads();

    if (isLast) {
      __threadfence();
      if (tid < NLAB*16) {                 // j x 16 block-slices
        const int j = tid >> 4, s = tid & 15;
        float acc = 0.0f;
        #pragma unroll
        for (int bb = 0; bb < 16; ++bb)
          acc += __hip_atomic_load(&ws_lp[(s*16 + bb)*16 + j],
                                   __ATOMIC_RELAXED, __HIP_MEMORY_SCOPE_AGENT);
        acc += __shfl_xor(acc, 1, 64);
        acc += __shfl_xor(acc, 2, 64);
        acc += __shfl_xor(acc, 4, 64);
        acc += __shfl_xor(acc, 8, 64);
        if (s == 0) slog[j] = acc + bout[j];
      }
      __syncthreads();
      if (tid == 0) {
        float m = slog[0];
        #pragma unroll
        for (int j = 1; j < NLAB; ++j) m = fmaxf(m, slog[j]);
        float ssum = 0.0f;
        float e[NLAB];
        #pragma unroll
        for (int j = 0; j < NLAB; ++j) { e[j] = __expf(slog[j] - m); ssum += e[j]; }
        const float inv = 1.0f / ssum;
        #pragma unroll
        for (int j = 0; j < NLAB; ++j) out[j] = e[j] * inv;
      }
    }
  }
}

extern "C" void kernel_launch(void* const* d_in, const int* in_sizes, int n_in,
                              void* d_out, int out_size, void* d_ws, size_t ws_size,
                              hipStream_t stream) {
  // inputs: 0=ts (unused), 1=logsigs (L,C), 2=x0 (D), 3=W_in (H,D), 4=b_in (H),
  //         5=vf_A (C,H), 6=W_out (10,H), 7=b_out (10)
  const float* logsigs = (const float*)d_in[1];
  const float* x0      = (const float*)d_in[2];
  const float* Win     = (const float*)d_in[3];
  const float* bin     = (const float*)d_in[4];
  const float* vfA     = (const float*)d_in[5];
  const float* Wout    = (const float*)d_in[6];
  const float* bout    = (const float*)d_in[7];
  float* out = (float*)d_out;

  // workspace layout (16B-aligned slices)
  float*    ws_p  = (float*)d_ws;                             // 256*4096 f32 = 4MB
  uint32_t* pBh   = (uint32_t*)(ws_p + (size_t)NCHUNK*HID);   // 256KB
  uint32_t* pBl   = pBh + (size_t)HID*NW;                     // 256KB
  float*    ws_lp = (float*)(pBl + (size_t)HID*NW);           // RBLK*16 f32
  uint32_t* cnt   = (uint32_t*)(ws_lp + (size_t)RBLK*16);

  // co-residency-safe grid: occupancy query (deterministic, capture-safe)
  int maxbpc = 0;
  if (hipOccupancyMaxActiveBlocksPerMultiprocessor(&maxbpc, fused_kernel, 256, 0)
      != hipSuccess || maxbpc < 1)
    maxbpc = 2;
  int nblk = maxbpc * 256;          // 256 CUs
  if (nblk > 1024) nblk = 1024;     // 4 blocks/CU target; multiple of 4

  void* args[] = {
    (void*)&logsigs, (void*)&vfA, (void*)&Win, (void*)&bin, (void*)&x0,
    (void*)&Wout, (void*)&bout, (void*)&ws_p, (void*)&pBh, (void*)&pBl,
    (void*)&ws_lp, (void*)&cnt, (void*)&out
  };
  hipLaunchCooperativeKernel(fused_kernel, dim3(nblk), dim3(256), args, 0, stream);
}

// Round 7
// 47.889 us; speedup vs baseline: 3.7896x; 3.7896x over previous
//
#include <hip/hip_runtime.h>
#include <hip/hip_bf16.h>
#include <stdint.h>

// LogLinearCDE: out = softmax(W_out @ (y0 * prod_l flows[l]) + b_out)
// flows[l,h] = 1 + sum_c logsigs[l,c]*vf_A[c,h];  y0 = W_in@x0 + b_in
// R7: 3 kernels, 2 launch gaps. (1) pack vf_A->bf16 hi/lo + zero counter.
// (2) MFMA partial products: R4 structure, CPB=2 at full (256,4) occupancy,
// R4 store layout ws_p[chunk][h]. (3) fused reduce+head with last-block
// fence pattern (validated R5/R6).

#define LSTEPS 16384
#define HID    4096
#define CC     17
#define NLAB   10
#define NW     16          // packed u32 words per col (K padded to 32 bf16)
#define NCHUNK 256
#define CR     64          // rows per chunk
#define APAD   20          // LDS A row stride in words (80B, 16B-aligned)
#define CPB    2           // chunks per partial block
#define NCG    (NCHUNK/CPB)
#define HPB    16          // h per reduce block
#define RBLK   256         // reduce blocks

typedef __attribute__((ext_vector_type(8))) short short8;
typedef __attribute__((ext_vector_type(4))) float f32x4;

static __device__ __forceinline__ unsigned short f2bf(float x) {
  __hip_bfloat16 h = __float2bfloat16(x);
  return *reinterpret_cast<unsigned short*>(&h);
}
static __device__ __forceinline__ float bf2f(unsigned short u) {
  __hip_bfloat16 h; *reinterpret_cast<unsigned short*>(&h) = u;
  return __bfloat162float(h);
}
static __device__ __forceinline__ uint32_t pack_hi(float v0, float v1) {
  return (uint32_t)f2bf(v0) | ((uint32_t)f2bf(v1) << 16);
}
static __device__ __forceinline__ uint32_t pack_lo(float v0, float v1) {
  float r0 = v0 - bf2f(f2bf(v0)), r1 = v1 - bf2f(f2bf(v1));
  return (uint32_t)f2bf(r0) | ((uint32_t)f2bf(r1) << 16);
}

// pre-pass: pack vf_A (C,H) into per-column bf16 hi/lo K-words; zero counter.
__global__ __launch_bounds__(256) void pack_vfA_kernel(
    const float* __restrict__ vfA,
    uint32_t* __restrict__ pBh, uint32_t* __restrict__ pBl,
    uint32_t* __restrict__ counter) {
  if (blockIdx.x == 0 && threadIdx.x == 0) *counter = 0u;
  const int c = blockIdx.x*256 + threadIdx.x;
  float v[2*NW];
  #pragma unroll
  for (int k = 0; k < 2*NW; ++k) v[k] = (k < CC) ? vfA[k*HID + c] : 0.0f;
  #pragma unroll
  for (int j = 0; j < NW; ++j) {
    pBh[(size_t)c*NW + j] = pack_hi(v[2*j], v[2*j+1]);
    pBl[(size_t)c*NW + j] = pack_lo(v[2*j], v[2*j+1]);
  }
}

// partial products over CR-row chunks via MFMA; CPB chunks per block,
// B fragments loaded once per nt and reused across the CPB chunks.
__global__ __launch_bounds__(256, 4) void partial_mfma_kernel(
    const float* __restrict__ logsigs, const uint32_t* __restrict__ pBh,
    const uint32_t* __restrict__ pBl, float* __restrict__ ws_p) {
  const int hb = blockIdx.x;        // 0..3 (1024 cols each)
  const int cg = blockIdx.y;        // 0..NCG-1
  const int chunk0 = cg * CPB;
  const int tid = threadIdx.x;

  __shared__ __align__(16) uint32_t sAh[CPB][CR][APAD], sAl[CPB][CR][APAD];

  // convert CPB chunks of logsig rows (64 x 17 each) to packed bf16 hi/lo
  const float* __restrict__ src = logsigs + (size_t)chunk0*CR*CC;
  for (int e = tid; e < CPB*CR*NW; e += 256) {
    const int cch = e >> 10;          // / (CR*NW)
    const int r   = (e >> 4) & (CR-1);
    const int j   = e & (NW-1);
    const int k0 = 2*j, k1 = k0 + 1;
    const int rr = cch*CR + r;
    const float v0 = (k0 < CC) ? src[rr*CC + k0] : 0.0f;
    const float v1 = (k1 < CC) ? src[rr*CC + k1] : 0.0f;
    sAh[cch][r][j] = pack_hi(v0, v1);
    sAl[cch][r][j] = pack_lo(v0, v1);
  }
  __syncthreads();

  const int wv = tid >> 6, lane = tid & 63;
  const int g = lane >> 4, cr = lane & 15;

  short8 Ah[CPB][4], Al[CPB][4];
  #pragma unroll
  for (int cc = 0; cc < CPB; ++cc)
    #pragma unroll
    for (int mt = 0; mt < 4; ++mt) {
      const int r = mt*16 + cr;
      Ah[cc][mt] = *reinterpret_cast<const short8*>(&sAh[cc][r][4*g]);
      Al[cc][mt] = *reinterpret_cast<const short8*>(&sAl[cc][r][4*g]);
    }

  const int cbase = hb*1024 + wv*256;
  #pragma unroll 2
  for (int nt = 0; nt < 16; ++nt) {
    const int c = cbase + nt*16 + cr;
    const short8 Bh = *reinterpret_cast<const short8*>(&pBh[(size_t)c*NW + 4*g]);
    const short8 Bl = *reinterpret_cast<const short8*>(&pBl[(size_t)c*NW + 4*g]);
    float pc[CPB];
    #pragma unroll
    for (int cc = 0; cc < CPB; ++cc) {
      float pcol = 1.0f;
      #pragma unroll
      for (int mt = 0; mt < 4; ++mt) {
        f32x4 acc = {0.0f, 0.0f, 0.0f, 0.0f};
        acc = __builtin_amdgcn_mfma_f32_16x16x32_bf16(Ah[cc][mt], Bh, acc, 0, 0, 0);
        acc = __builtin_amdgcn_mfma_f32_16x16x32_bf16(Ah[cc][mt], Bl, acc, 0, 0, 0);
        acc = __builtin_amdgcn_mfma_f32_16x16x32_bf16(Al[cc][mt], Bh, acc, 0, 0, 0);
        pcol *= (1.0f + acc[0]) * (1.0f + acc[1]) * (1.0f + acc[2]) * (1.0f + acc[3]);
      }
      pc[cc] = pcol;
    }
    #pragma unroll
    for (int cc = 0; cc < CPB; ++cc) {
      pc[cc] *= __shfl_xor(pc[cc], 16, 64);
      pc[cc] *= __shfl_xor(pc[cc], 32, 64);
      if (g == 0) ws_p[(size_t)(chunk0+cc)*HID + c] = pc[cc];
    }
  }
}

// fused: per-h product over all chunks, y0, logits, last-block softmax.
__global__ __launch_bounds__(256) void reduce_head_kernel(
    const float* __restrict__ ws_p, const float* __restrict__ Win,
    const float* __restrict__ bin,  const float* __restrict__ x0,
    const float* __restrict__ Wout, const float* __restrict__ bout,
    float* __restrict__ ws_lp, uint32_t* __restrict__ counter,
    float* __restrict__ out) {
  const int b = blockIdx.x, tid = threadIdx.x;
  const int h0 = b * HPB;
  const int hh = tid & 15, sl = tid >> 4;

  __shared__ float sp[HPB][17];
  __shared__ float sy[HPB];
  __shared__ float slog[NLAB];
  __shared__ bool isLast;

  // slice product: thread (hh,sl) multiplies chunks sl*16..sl*16+15 for h0+hh
  {
    float p = 1.0f;
    #pragma unroll
    for (int i = 0; i < 16; ++i)
      p *= ws_p[(size_t)(sl*16 + i)*HID + h0 + hh];
    sp[hh][sl] = p;
  }
  __syncthreads();

  if (tid < HPB) {
    float P = 1.0f;
    #pragma unroll
    for (int s = 0; s < 16; ++s) P *= sp[tid][s];
    const int h = h0 + tid;
    const float4* __restrict__ wrow = reinterpret_cast<const float4*>(Win + (size_t)h*16);
    float y = bin[h];
    #pragma unroll
    for (int q = 0; q < 4; ++q) {
      float4 w = wrow[q];
      y = fmaf(w.x, x0[q*4+0], y);
      y = fmaf(w.y, x0[q*4+1], y);
      y = fmaf(w.z, x0[q*4+2], y);
      y = fmaf(w.w, x0[q*4+3], y);
    }
    sy[tid] = y * P;
  }
  __syncthreads();

  // partial logits for this block's 16 h (fixed shfl order -> deterministic)
  if (tid < NLAB*HPB) {                     // 160 threads
    const int j = tid >> 4, k = tid & 15;
    float v = Wout[(size_t)j*HID + h0 + k] * sy[k];
    v += __shfl_xor(v, 1, 64);
    v += __shfl_xor(v, 2, 64);
    v += __shfl_xor(v, 4, 64);
    v += __shfl_xor(v, 8, 64);
    if (k == 0) ws_lp[b*16 + j] = v;
  }
  __threadfence();
  __syncthreads();
  if (tid == 0) isLast = (atomicAdd(counter, 1u) == RBLK - 1);
  __syncthreads();

  if (isLast) {
    __threadfence();
    if (tid < NLAB*16) {                    // j x 16 block-slices
      const int j = tid >> 4, s = tid & 15;
      float acc = 0.0f;
      #pragma unroll
      for (int bb = 0; bb < 16; ++bb)
        acc += __hip_atomic_load(&ws_lp[(s*16 + bb)*16 + j],
                                 __ATOMIC_RELAXED, __HIP_MEMORY_SCOPE_AGENT);
      acc += __shfl_xor(acc, 1, 64);
      acc += __shfl_xor(acc, 2, 64);
      acc += __shfl_xor(acc, 4, 64);
      acc += __shfl_xor(acc, 8, 64);
      if (s == 0) slog[j] = acc + bout[j];
    }
    __syncthreads();
    if (tid == 0) {
      float m = slog[0];
      #pragma unroll
      for (int j = 1; j < NLAB; ++j) m = fmaxf(m, slog[j]);
      float ssum = 0.0f;
      float e[NLAB];
      #pragma unroll
      for (int j = 0; j < NLAB; ++j) { e[j] = __expf(slog[j] - m); ssum += e[j]; }
      const float inv = 1.0f / ssum;
      #pragma unroll
      for (int j = 0; j < NLAB; ++j) out[j] = e[j] * inv;
    }
  }
}

extern "C" void kernel_launch(void* const* d_in, const int* in_sizes, int n_in,
                              void* d_out, int out_size, void* d_ws, size_t ws_size,
                              hipStream_t stream) {
  // inputs: 0=ts (unused), 1=logsigs (L,C), 2=x0 (D), 3=W_in (H,D), 4=b_in (H),
  //         5=vf_A (C,H), 6=W_out (10,H), 7=b_out (10)
  const float* logsigs = (const float*)d_in[1];
  const float* x0      = (const float*)d_in[2];
  const float* Win     = (const float*)d_in[3];
  const float* bin     = (const float*)d_in[4];
  const float* vfA     = (const float*)d_in[5];
  const float* Wout    = (const float*)d_in[6];
  const float* bout    = (const float*)d_in[7];
  float* out = (float*)d_out;

  // workspace layout (16B-aligned slices)
  float*    ws_p  = (float*)d_ws;                            // 256*4096 f32 = 4MB
  uint32_t* pBh   = (uint32_t*)(ws_p + (size_t)NCHUNK*HID);  // 256KB
  uint32_t* pBl   = pBh + (size_t)HID*NW;                    // 256KB
  float*    ws_lp = (float*)(pBl + (size_t)HID*NW);          // RBLK*16 f32
  uint32_t* cnt   = (uint32_t*)(ws_lp + (size_t)RBLK*16);

  pack_vfA_kernel<<<HID/256, 256, 0, stream>>>(vfA, pBh, pBl, cnt);
  partial_mfma_kernel<<<dim3(4, NCG), 256, 0, stream>>>(logsigs, pBh, pBl, ws_p);
  reduce_head_kernel<<<RBLK, 256, 0, stream>>>(ws_p, Win, bin, x0, Wout, bout,
                                               ws_lp, cnt, out);
}

// Round 8
// 44.792 us; speedup vs baseline: 4.0516x; 1.0691x over previous
//
#include <hip/hip_runtime.h>
#include <hip/hip_bf16.h>
#include <stdint.h>

// LogLinearCDE: out = softmax(W_out @ (y0 * prod_l flows[l]) + b_out)
// flows[l,h] = 1 + sum_c logsigs[l,c]*vf_A[c,h];  y0 = W_in@x0 + b_in
// R8: 3 kernels. (1) pack vf_A->bf16 hi/lo + zero counter. (2) MFMA partial
// products: EXACT R4 structure (CPB=1, (256,4), no spills). (3) fused
// reduce+head with last-block fence pattern.

#define LSTEPS 16384
#define HID    4096
#define CC     17
#define NLAB   10
#define NW     16          // packed u32 words per col (K padded to 32 bf16)
#define NCHUNK 256
#define CR     64          // rows per chunk
#define APAD   20          // LDS A row stride in words (80B, 16B-aligned)
#define HPB    16          // h per reduce block
#define RBLK   256         // reduce blocks

typedef __attribute__((ext_vector_type(8))) short short8;
typedef __attribute__((ext_vector_type(4))) float f32x4;

static __device__ __forceinline__ unsigned short f2bf(float x) {
  __hip_bfloat16 h = __float2bfloat16(x);
  return *reinterpret_cast<unsigned short*>(&h);
}
static __device__ __forceinline__ float bf2f(unsigned short u) {
  __hip_bfloat16 h; *reinterpret_cast<unsigned short*>(&h) = u;
  return __bfloat162float(h);
}
static __device__ __forceinline__ uint32_t pack_hi(float v0, float v1) {
  return (uint32_t)f2bf(v0) | ((uint32_t)f2bf(v1) << 16);
}
static __device__ __forceinline__ uint32_t pack_lo(float v0, float v1) {
  float r0 = v0 - bf2f(f2bf(v0)), r1 = v1 - bf2f(f2bf(v1));
  return (uint32_t)f2bf(r0) | ((uint32_t)f2bf(r1) << 16);
}

// pre-pass: pack vf_A (C,H) into per-column bf16 hi/lo K-words; zero counter.
__global__ __launch_bounds__(256) void pack_vfA_kernel(
    const float* __restrict__ vfA,
    uint32_t* __restrict__ pBh, uint32_t* __restrict__ pBl,
    uint32_t* __restrict__ counter) {
  if (blockIdx.x == 0 && threadIdx.x == 0) *counter = 0u;
  const int c = blockIdx.x*256 + threadIdx.x;
  float v[2*NW];
  #pragma unroll
  for (int k = 0; k < 2*NW; ++k) v[k] = (k < CC) ? vfA[k*HID + c] : 0.0f;
  #pragma unroll
  for (int j = 0; j < NW; ++j) {
    pBh[(size_t)c*NW + j] = pack_hi(v[2*j], v[2*j+1]);
    pBl[(size_t)c*NW + j] = pack_lo(v[2*j], v[2*j+1]);
  }
}

// partial products over 64-row chunks via MFMA (exact R4 structure)
__global__ __launch_bounds__(256, 4) void partial_mfma_kernel(
    const float* __restrict__ logsigs, const uint32_t* __restrict__ pBh,
    const uint32_t* __restrict__ pBl, float* __restrict__ ws_p) {
  const int hb = blockIdx.x;        // 0..3 (1024 cols each)
  const int chunk = blockIdx.y;     // 0..255
  const int tid = threadIdx.x;

  __shared__ __align__(16) uint32_t sAh[CR][APAD], sAl[CR][APAD];

  // convert this chunk's logsig rows (64 x 17) to packed bf16 hi/lo words
  const float* __restrict__ src = logsigs + (size_t)chunk*CR*CC;
  for (int e = tid; e < CR*NW; e += 256) {
    const int r = e >> 4, j = e & (NW-1);
    const int k0 = 2*j, k1 = k0 + 1;
    const float v0 = (k0 < CC) ? src[r*CC + k0] : 0.0f;
    const float v1 = (k1 < CC) ? src[r*CC + k1] : 0.0f;
    sAh[r][j] = pack_hi(v0, v1);
    sAl[r][j] = pack_lo(v0, v1);
  }
  __syncthreads();

  const int wv = tid >> 6, lane = tid & 63;
  const int g = lane >> 4, cr = lane & 15;

  short8 Ah[4], Al[4];
  #pragma unroll
  for (int mt = 0; mt < 4; ++mt) {
    const int r = mt*16 + cr;
    Ah[mt] = *reinterpret_cast<const short8*>(&sAh[r][4*g]);
    Al[mt] = *reinterpret_cast<const short8*>(&sAl[r][4*g]);
  }

  const int cbase = hb*1024 + wv*256;
  #pragma unroll 2
  for (int nt = 0; nt < 16; ++nt) {
    const int c = cbase + nt*16 + cr;
    const short8 Bh = *reinterpret_cast<const short8*>(&pBh[(size_t)c*NW + 4*g]);
    const short8 Bl = *reinterpret_cast<const short8*>(&pBl[(size_t)c*NW + 4*g]);
    float pcol = 1.0f;
    #pragma unroll
    for (int mt = 0; mt < 4; ++mt) {
      f32x4 acc = {0.0f, 0.0f, 0.0f, 0.0f};
      acc = __builtin_amdgcn_mfma_f32_16x16x32_bf16(Ah[mt], Bh, acc, 0, 0, 0);
      acc = __builtin_amdgcn_mfma_f32_16x16x32_bf16(Ah[mt], Bl, acc, 0, 0, 0);
      acc = __builtin_amdgcn_mfma_f32_16x16x32_bf16(Al[mt], Bh, acc, 0, 0, 0);
      pcol *= (1.0f + acc[0]) * (1.0f + acc[1]) * (1.0f + acc[2]) * (1.0f + acc[3]);
    }
    pcol *= __shfl_xor(pcol, 16, 64);
    pcol *= __shfl_xor(pcol, 32, 64);
    if (g == 0) ws_p[(size_t)chunk*HID + c] = pcol;
  }
}

// fused: per-h product over all chunks, y0, logits, last-block softmax.
__global__ __launch_bounds__(256) void reduce_head_kernel(
    const float* __restrict__ ws_p, const float* __restrict__ Win,
    const float* __restrict__ bin,  const float* __restrict__ x0,
    const float* __restrict__ Wout, const float* __restrict__ bout,
    float* __restrict__ ws_lp, uint32_t* __restrict__ counter,
    float* __restrict__ out) {
  const int b = blockIdx.x, tid = threadIdx.x;
  const int h0 = b * HPB;
  const int hh = tid & 15, sl = tid >> 4;

  __shared__ float sp[HPB][17];
  __shared__ float sy[HPB];
  __shared__ float slog[NLAB];
  __shared__ bool isLast;

  // slice product: thread (hh,sl) multiplies chunks sl*16..sl*16+15 for h0+hh
  {
    float p = 1.0f;
    #pragma unroll
    for (int i = 0; i < 16; ++i)
      p *= ws_p[(size_t)(sl*16 + i)*HID + h0 + hh];
    sp[hh][sl] = p;
  }
  __syncthreads();

  if (tid < HPB) {
    float P = 1.0f;
    #pragma unroll
    for (int s = 0; s < 16; ++s) P *= sp[tid][s];
    const int h = h0 + tid;
    const float4* __restrict__ wrow = reinterpret_cast<const float4*>(Win + (size_t)h*16);
    float y = bin[h];
    #pragma unroll
    for (int q = 0; q < 4; ++q) {
      float4 w = wrow[q];
      y = fmaf(w.x, x0[q*4+0], y);
      y = fmaf(w.y, x0[q*4+1], y);
      y = fmaf(w.z, x0[q*4+2], y);
      y = fmaf(w.w, x0[q*4+3], y);
    }
    sy[tid] = y * P;
  }
  __syncthreads();

  // partial logits for this block's 16 h (fixed shfl order -> deterministic)
  if (tid < NLAB*HPB) {                     // 160 threads
    const int j = tid >> 4, k = tid & 15;
    float v = Wout[(size_t)j*HID + h0 + k] * sy[k];
    v += __shfl_xor(v, 1, 64);
    v += __shfl_xor(v, 2, 64);
    v += __shfl_xor(v, 4, 64);
    v += __shfl_xor(v, 8, 64);
    if (k == 0) ws_lp[b*16 + j] = v;
  }
  __threadfence();
  __syncthreads();
  if (tid == 0) isLast = (atomicAdd(counter, 1u) == RBLK - 1);
  __syncthreads();

  if (isLast) {
    __threadfence();
    if (tid < NLAB*16) {                    // j x 16 block-slices
      const int j = tid >> 4, s = tid & 15;
      float acc = 0.0f;
      #pragma unroll
      for (int bb = 0; bb < 16; ++bb)
        acc += __hip_atomic_load(&ws_lp[(s*16 + bb)*16 + j],
                                 __ATOMIC_RELAXED, __HIP_MEMORY_SCOPE_AGENT);
      acc += __shfl_xor(acc, 1, 64);
      acc += __shfl_xor(acc, 2, 64);
      acc += __shfl_xor(acc, 4, 64);
      acc += __shfl_xor(acc, 8, 64);
      if (s == 0) slog[j] = acc + bout[j];
    }
    __syncthreads();
    if (tid == 0) {
      float m = slog[0];
      #pragma unroll
      for (int j = 1; j < NLAB; ++j) m = fmaxf(m, slog[j]);
      float ssum = 0.0f;
      float e[NLAB];
      #pragma unroll
      for (int j = 0; j < NLAB; ++j) { e[j] = __expf(slog[j] - m); ssum += e[j]; }
      const float inv = 1.0f / ssum;
      #pragma unroll
      for (int j = 0; j < NLAB; ++j) out[j] = e[j] * inv;
    }
  }
}

extern "C" void kernel_launch(void* const* d_in, const int* in_sizes, int n_in,
                              void* d_out, int out_size, void* d_ws, size_t ws_size,
                              hipStream_t stream) {
  // inputs: 0=ts (unused), 1=logsigs (L,C), 2=x0 (D), 3=W_in (H,D), 4=b_in (H),
  //         5=vf_A (C,H), 6=W_out (10,H), 7=b_out (10)
  const float* logsigs = (const float*)d_in[1];
  const float* x0      = (const float*)d_in[2];
  const float* Win     = (const float*)d_in[3];
  const float* bin     = (const float*)d_in[4];
  const float* vfA     = (const float*)d_in[5];
  const float* Wout    = (const float*)d_in[6];
  const float* bout    = (const float*)d_in[7];
  float* out = (float*)d_out;

  // workspace layout (16B-aligned slices)
  float*    ws_p  = (float*)d_ws;                            // 256*4096 f32 = 4MB
  uint32_t* pBh   = (uint32_t*)(ws_p + (size_t)NCHUNK*HID);  // 256KB
  uint32_t* pBl   = pBh + (size_t)HID*NW;                    // 256KB
  float*    ws_lp = (float*)(pBl + (size_t)HID*NW);          // RBLK*16 f32
  uint32_t* cnt   = (uint32_t*)(ws_lp + (size_t)RBLK*16);

  pack_vfA_kernel<<<HID/256, 256, 0, stream>>>(vfA, pBh, pBl, cnt);
  partial_mfma_kernel<<<dim3(4, NCHUNK), 256, 0, stream>>>(logsigs, pBh, pBl, ws_p);
  reduce_head_kernel<<<RBLK, 256, 0, stream>>>(ws_p, Win, bin, x0, Wout, bout,
                                               ws_lp, cnt, out);
}

// Round 9
// 29.348 us; speedup vs baseline: 6.1837x; 1.5263x over previous
//
#include <hip/hip_runtime.h>
#include <hip/hip_bf16.h>
#include <stdint.h>

// LogLinearCDE: out = softmax(W_out @ (y0 * prod_l flows[l]) + b_out)
// flows[l,h] = 1 + sum_c logsigs[l,c]*vf_A[c,h];  y0 = W_in@x0 + b_in
// R9: 4 kernels, NO device-scope fences (XCD L2 writeback is expensive).
// (1) pack vf_A->bf16 hi/lo. (2) MFMA partial products (R4 structure).
// (3) tailA: per-h chunk product + y0 + per-block partial logits.
// (4) tailB: 1 block sums partials + softmax. Kernel-boundary sync only.

#define LSTEPS 16384
#define HID    4096
#define CC     17
#define NLAB   10
#define NW     16          // packed u32 words per col (K padded to 32 bf16)
#define NCHUNK 256
#define CR     64          // rows per chunk
#define APAD   20          // LDS A row stride in words (80B, 16B-aligned)
#define HPB    16          // h per tailA block
#define RBLK   256         // tailA blocks

typedef __attribute__((ext_vector_type(8))) short short8;
typedef __attribute__((ext_vector_type(4))) float f32x4;

static __device__ __forceinline__ unsigned short f2bf(float x) {
  __hip_bfloat16 h = __float2bfloat16(x);
  return *reinterpret_cast<unsigned short*>(&h);
}
static __device__ __forceinline__ float bf2f(unsigned short u) {
  __hip_bfloat16 h; *reinterpret_cast<unsigned short*>(&h) = u;
  return __bfloat162float(h);
}
static __device__ __forceinline__ uint32_t pack_hi(float v0, float v1) {
  return (uint32_t)f2bf(v0) | ((uint32_t)f2bf(v1) << 16);
}
static __device__ __forceinline__ uint32_t pack_lo(float v0, float v1) {
  float r0 = v0 - bf2f(f2bf(v0)), r1 = v1 - bf2f(f2bf(v1));
  return (uint32_t)f2bf(r0) | ((uint32_t)f2bf(r1) << 16);
}

// pre-pass: pack vf_A (C,H) into per-column bf16 hi/lo K-words.
__global__ __launch_bounds__(256) void pack_vfA_kernel(
    const float* __restrict__ vfA,
    uint32_t* __restrict__ pBh, uint32_t* __restrict__ pBl) {
  const int c = blockIdx.x*256 + threadIdx.x;
  float v[2*NW];
  #pragma unroll
  for (int k = 0; k < 2*NW; ++k) v[k] = (k < CC) ? vfA[k*HID + c] : 0.0f;
  #pragma unroll
  for (int j = 0; j < NW; ++j) {
    pBh[(size_t)c*NW + j] = pack_hi(v[2*j], v[2*j+1]);
    pBl[(size_t)c*NW + j] = pack_lo(v[2*j], v[2*j+1]);
  }
}

// partial products over 64-row chunks via MFMA (exact R4 structure)
__global__ __launch_bounds__(256, 4) void partial_mfma_kernel(
    const float* __restrict__ logsigs, const uint32_t* __restrict__ pBh,
    const uint32_t* __restrict__ pBl, float* __restrict__ ws_p) {
  const int hb = blockIdx.x;        // 0..3 (1024 cols each)
  const int chunk = blockIdx.y;     // 0..255
  const int tid = threadIdx.x;

  __shared__ __align__(16) uint32_t sAh[CR][APAD], sAl[CR][APAD];

  // convert this chunk's logsig rows (64 x 17) to packed bf16 hi/lo words
  const float* __restrict__ src = logsigs + (size_t)chunk*CR*CC;
  for (int e = tid; e < CR*NW; e += 256) {
    const int r = e >> 4, j = e & (NW-1);
    const int k0 = 2*j, k1 = k0 + 1;
    const float v0 = (k0 < CC) ? src[r*CC + k0] : 0.0f;
    const float v1 = (k1 < CC) ? src[r*CC + k1] : 0.0f;
    sAh[r][j] = pack_hi(v0, v1);
    sAl[r][j] = pack_lo(v0, v1);
  }
  __syncthreads();

  const int wv = tid >> 6, lane = tid & 63;
  const int g = lane >> 4, cr = lane & 15;

  short8 Ah[4], Al[4];
  #pragma unroll
  for (int mt = 0; mt < 4; ++mt) {
    const int r = mt*16 + cr;
    Ah[mt] = *reinterpret_cast<const short8*>(&sAh[r][4*g]);
    Al[mt] = *reinterpret_cast<const short8*>(&sAl[r][4*g]);
  }

  const int cbase = hb*1024 + wv*256;
  #pragma unroll 2
  for (int nt = 0; nt < 16; ++nt) {
    const int c = cbase + nt*16 + cr;
    const short8 Bh = *reinterpret_cast<const short8*>(&pBh[(size_t)c*NW + 4*g]);
    const short8 Bl = *reinterpret_cast<const short8*>(&pBl[(size_t)c*NW + 4*g]);
    float pcol = 1.0f;
    #pragma unroll
    for (int mt = 0; mt < 4; ++mt) {
      f32x4 acc = {0.0f, 0.0f, 0.0f, 0.0f};
      acc = __builtin_amdgcn_mfma_f32_16x16x32_bf16(Ah[mt], Bh, acc, 0, 0, 0);
      acc = __builtin_amdgcn_mfma_f32_16x16x32_bf16(Ah[mt], Bl, acc, 0, 0, 0);
      acc = __builtin_amdgcn_mfma_f32_16x16x32_bf16(Al[mt], Bh, acc, 0, 0, 0);
      pcol *= (1.0f + acc[0]) * (1.0f + acc[1]) * (1.0f + acc[2]) * (1.0f + acc[3]);
    }
    pcol *= __shfl_xor(pcol, 16, 64);
    pcol *= __shfl_xor(pcol, 32, 64);
    if (g == 0) ws_p[(size_t)chunk*HID + c] = pcol;
  }
}

// tailA: per-h product over all chunks, y0, per-block partial logits.
__global__ __launch_bounds__(256) void tailA_kernel(
    const float* __restrict__ ws_p, const float* __restrict__ Win,
    const float* __restrict__ bin,  const float* __restrict__ x0,
    const float* __restrict__ Wout, float* __restrict__ ws_lp) {
  const int b = blockIdx.x, tid = threadIdx.x;
  const int h0 = b * HPB;
  const int hh = tid & 15, sl = tid >> 4;

  __shared__ float sp[HPB][17];
  __shared__ float sy[HPB];

  // slice product: thread (hh,sl) multiplies chunks sl*16..sl*16+15 for h0+hh
  {
    float p = 1.0f;
    #pragma unroll
    for (int i = 0; i < 16; ++i)
      p *= ws_p[(size_t)(sl*16 + i)*HID + h0 + hh];
    sp[hh][sl] = p;
  }
  __syncthreads();

  if (tid < HPB) {
    float P = 1.0f;
    #pragma unroll
    for (int s = 0; s < 16; ++s) P *= sp[tid][s];
    const int h = h0 + tid;
    const float4* __restrict__ wrow = reinterpret_cast<const float4*>(Win + (size_t)h*16);
    float y = bin[h];
    #pragma unroll
    for (int q = 0; q < 4; ++q) {
      float4 w = wrow[q];
      y = fmaf(w.x, x0[q*4+0], y);
      y = fmaf(w.y, x0[q*4+1], y);
      y = fmaf(w.z, x0[q*4+2], y);
      y = fmaf(w.w, x0[q*4+3], y);
    }
    sy[tid] = y * P;
  }
  __syncthreads();

  // partial logits for this block's 16 h (fixed shfl order -> deterministic)
  if (tid < NLAB*HPB) {                     // 160 threads
    const int j = tid >> 4, k = tid & 15;
    float v = Wout[(size_t)j*HID + h0 + k] * sy[k];
    v += __shfl_xor(v, 1, 64);
    v += __shfl_xor(v, 2, 64);
    v += __shfl_xor(v, 4, 64);
    v += __shfl_xor(v, 8, 64);
    if (k == 0) ws_lp[b*16 + j] = v;
  }
}

// tailB: one block sums 256x10 partial logits (deterministic order) + softmax
__global__ __launch_bounds__(256) void tailB_kernel(
    const float* __restrict__ ws_lp, const float* __restrict__ bout,
    float* __restrict__ out) {
  const int tid = threadIdx.x;
  __shared__ float slog[NLAB];

  if (tid < NLAB*16) {                      // j x 16 block-slices
    const int j = tid >> 4, s = tid & 15;
    float acc = 0.0f;
    #pragma unroll
    for (int bb = 0; bb < 16; ++bb)
      acc += ws_lp[(s*16 + bb)*16 + j];
    acc += __shfl_xor(acc, 1, 64);
    acc += __shfl_xor(acc, 2, 64);
    acc += __shfl_xor(acc, 4, 64);
    acc += __shfl_xor(acc, 8, 64);
    if (s == 0) slog[j] = acc + bout[j];
  }
  __syncthreads();
  if (tid == 0) {
    float m = slog[0];
    #pragma unroll
    for (int j = 1; j < NLAB; ++j) m = fmaxf(m, slog[j]);
    float ssum = 0.0f;
    float e[NLAB];
    #pragma unroll
    for (int j = 0; j < NLAB; ++j) { e[j] = __expf(slog[j] - m); ssum += e[j]; }
    const float inv = 1.0f / ssum;
    #pragma unroll
    for (int j = 0; j < NLAB; ++j) out[j] = e[j] * inv;
  }
}

extern "C" void kernel_launch(void* const* d_in, const int* in_sizes, int n_in,
                              void* d_out, int out_size, void* d_ws, size_t ws_size,
                              hipStream_t stream) {
  // inputs: 0=ts (unused), 1=logsigs (L,C), 2=x0 (D), 3=W_in (H,D), 4=b_in (H),
  //         5=vf_A (C,H), 6=W_out (10,H), 7=b_out (10)
  const float* logsigs = (const float*)d_in[1];
  const float* x0      = (const float*)d_in[2];
  const float* Win     = (const float*)d_in[3];
  const float* bin     = (const float*)d_in[4];
  const float* vfA     = (const float*)d_in[5];
  const float* Wout    = (const float*)d_in[6];
  const float* bout    = (const float*)d_in[7];
  float* out = (float*)d_out;

  // workspace layout (16B-aligned slices)
  float*    ws_p  = (float*)d_ws;                            // 256*4096 f32 = 4MB
  uint32_t* pBh   = (uint32_t*)(ws_p + (size_t)NCHUNK*HID);  // 256KB
  uint32_t* pBl   = pBh + (size_t)HID*NW;                    // 256KB
  float*    ws_lp = (float*)(pBl + (size_t)HID*NW);          // RBLK*16 f32

  pack_vfA_kernel<<<HID/256, 256, 0, stream>>>(vfA, pBh, pBl);
  partial_mfma_kernel<<<dim3(4, NCHUNK), 256, 0, stream>>>(logsigs, pBh, pBl, ws_p);
  tailA_kernel<<<RBLK, 256, 0, stream>>>(ws_p, Win, bin, x0, Wout, ws_lp);
  tailB_kernel<<<1, 256, 0, stream>>>(ws_lp, bout, out);
}